// Round 1
// baseline (187.806 us; speedup 1.0000x reference)
//
#include <hip/hip_runtime.h>
#include <math.h>

// Shapes (from setup_inputs): B=2, N=512, C=256, H=128, W=224.
// B,N,C derived from in_sizes at launch; H,W are device scalars we cannot
// read host-side without a sync, so they are hardcoded (grid depends on them).
#define TW 56   // pixels per strip (224 = 4*56)
#define GC 32   // gaussians per LDS weight chunk
#define MAXN 1024

// ---------------- kernel 1: per-gaussian projection/prep ----------------
__global__ void prep_kernel(const float* __restrict__ gd,
                            const float* __restrict__ Kmat,
                            float4* __restrict__ bbox,
                            float4* __restrict__ prm,
                            int N, int B, float Wf, float Hf) {
  int i = blockIdx.x * blockDim.x + threadIdx.x;
  if (i >= B * N) return;
  int b = i / N;
  const float* g = gd + (size_t)i * 14;
  float X = g[0], Y = g[1], Z = g[2];
  float sigx = g[5], sigy = g[6], wt = g[12];
  const float* K = Kmat + (size_t)b * 9;
  float p0 = K[0]*X + K[1]*Y + K[2]*Z;
  float p1 = K[3]*X + K[4]*Y + K[5]*Z;
  float p2 = K[6]*X + K[7]*Y + K[8]*Z;
  float denom = p2 + 1e-6f;
  float p2x = p0 / denom, p2y = p1 / denom;
  float scale_x = Wf / K[2] * 0.5f;   // W / K[0,2] / 2
  float scale_y = Hf / K[5] * 0.5f;   // H / K[1,2] / 2
  float cx = p2x * scale_x;
  float cy = p2y * scale_y;
  bool valid = Z > 0.1f;
  bool inb = (cx >= 0.f) && (cx < Wf) && (cy >= 0.f) && (cy < Hf);
  bool active = valid && inb;
  float sxv = fmaxf(sigx * scale_x, 1.f);
  float syv = fmaxf(sigy * scale_y, 1.f);
  float wn = active ? wt : 0.f;
  float avg = 0.5f * (sxv + syv);
  if (active && wn != 0.f) {
    bbox[i] = make_float4(cx, cy, 3.f * sxv, 3.f * syv);
  } else {
    bbox[i] = make_float4(-1e30f, -1e30f, 0.f, 0.f);  // never culled-in
  }
  prm[i] = make_float4(1.f / sxv, 1.f / syv, wn, avg);
}

// ---------------- kernel 2: MLP h = relu(pf@W1^T+b1)@W2^T+b2 ----------------
__global__ __launch_bounds__(256) void mlp_kernel(
    const float* __restrict__ pf, const float* __restrict__ W1,
    const float* __restrict__ b1, const float* __restrict__ W2,
    const float* __restrict__ b2, float* __restrict__ hout) {
  int pt = blockIdx.x;      // global point id in [0, B*N)
  int t = threadIdx.x;      // channel (C==256)
  __shared__ __align__(16) float xs[256];
  xs[t] = pf[(size_t)pt * 256 + t];
  __syncthreads();
  float a = b1[t];
  const float* w1r = W1 + (size_t)t * 256;
  #pragma unroll 8
  for (int k = 0; k < 256; k += 4) {
    float4 w = *(const float4*)(w1r + k);
    float4 x = *(const float4*)(xs + k);
    a += w.x * x.x + w.y * x.y + w.z * x.z + w.w * x.w;
  }
  a = fmaxf(a, 0.f);
  __syncthreads();
  xs[t] = a;
  __syncthreads();
  float a2 = b2[t];
  const float* w2r = W2 + (size_t)t * 256;
  #pragma unroll 8
  for (int k = 0; k < 256; k += 4) {
    float4 w = *(const float4*)(w2r + k);
    float4 x = *(const float4*)(xs + k);
    a2 += w.x * x.x + w.y * x.y + w.z * x.z + w.w * x.w;
  }
  hout[(size_t)pt * 256 + t] = a2;
}

// ---------------- kernel 3: gather-splat per 1x56 pixel strip ----------------
// block = 256 threads (thread = channel); one block owns strip (b,row,x0..x0+55)
__global__ __launch_bounds__(256) void splat_kernel(
    const float4* __restrict__ bbox, const float4* __restrict__ prm,
    const float* __restrict__ hfeat, float* __restrict__ fout,
    float* __restrict__ unc_out, float* __restrict__ dens_out,
    int N, int C, int H, int W) {
  const int t = threadIdx.x;
  const int b = blockIdx.z;
  const int row = blockIdx.y;
  const int x0 = blockIdx.x * TW;
  const int HW = H * W;

  __shared__ int glist[MAXN];
  __shared__ __align__(16) float wlds[GC][TW];
  __shared__ float dens_s[TW], unc_s[TW], invd_s[TW], avgs_s[GC];
  __shared__ int wcnt[4];

  const float rf = (float)row;
  const float xlo = (float)x0, xhi = (float)(x0 + TW - 1);
  const int lane = t & 63, wave = t >> 6;
  const unsigned long long lmask = (1ull << lane) - 1ull;

  // ---- deterministic ordered cull (ballot + cross-wave prefix) ----
  int listlen = 0;
  for (int gb = 0; gb < N; gb += 256) {
    int g = gb + t;
    bool f = false;
    if (g < N) {
      float4 bb = bbox[(size_t)b * N + g];
      f = (bb.y - bb.w <= rf) && (bb.y + bb.w >= rf) &&
          (bb.x + bb.z >= xlo) && (bb.x - bb.z <= xhi);
    }
    unsigned long long m = __ballot(f);
    if (lane == 0) wcnt[wave] = __popcll(m);
    __syncthreads();
    int pre = 0;
    #pragma unroll
    for (int wv = 0; wv < 4; ++wv) pre += (wv < wave) ? wcnt[wv] : 0;
    int tot = wcnt[0] + wcnt[1] + wcnt[2] + wcnt[3];
    if (f) glist[listlen + pre + __popcll(m & lmask)] = g;
    __syncthreads();
    listlen += tot;
  }

  if (t < TW) { dens_s[t] = 0.f; unc_s[t] = 0.f; }
  float acc[TW];
  #pragma unroll
  for (int p = 0; p < TW; ++p) acc[p] = 0.f;
  __syncthreads();

  // ---- chunked accumulation ----
  for (int gs = 0; gs < listlen; gs += GC) {
    int gc = min(GC, listlen - gs);
    if (t < gc) avgs_s[t] = prm[(size_t)b * N + glist[gs + t]].w;
    // weights for gc gaussians x TW pixels
    for (int idx = t; idx < gc * TW; idx += 256) {
      int gi = idx / TW, p = idx - gi * TW;
      int g = glist[gs + gi];
      float4 bb = bbox[(size_t)b * N + g];
      float4 pr = prm[(size_t)b * N + g];
      float dx = (xlo + (float)p - bb.x) * pr.x;
      float dy = (rf - bb.y) * pr.y;
      float d = dx * dx + dy * dy;
      wlds[gi][p] = (d < 9.f) ? __expf(-0.5f * d) * pr.z : 0.f;
    }
    __syncthreads();
    // per-pixel density / uncertainty
    if (t < TW) {
      float dsum = dens_s[t], usum = unc_s[t];
      for (int gi = 0; gi < gc; ++gi) {
        float w = wlds[gi][t];
        dsum += w;
        usum += w * avgs_s[gi];
      }
      dens_s[t] = dsum; unc_s[t] = usum;
    }
    // per-channel feature accumulation (broadcast LDS reads)
    for (int gi = 0; gi < gc; ++gi) {
      float hv = hfeat[((size_t)b * N + glist[gs + gi]) * C + t];
      const float4* wr = (const float4*)&wlds[gi][0];
      #pragma unroll
      for (int p4 = 0; p4 < TW / 4; ++p4) {
        float4 w4 = wr[p4];
        acc[4 * p4 + 0] += w4.x * hv;
        acc[4 * p4 + 1] += w4.y * hv;
        acc[4 * p4 + 2] += w4.z * hv;
        acc[4 * p4 + 3] += w4.w * hv;
      }
    }
    __syncthreads();
  }

  // ---- normalize + write ----
  if (t < TW) {
    float dc = fmaxf(dens_s[t], 1e-6f);
    float inv = 1.f / dc;
    invd_s[t] = inv;
    size_t pix = (size_t)b * HW + (size_t)row * W + x0 + t;
    unc_out[pix] = unc_s[t] * inv;
    dens_out[pix] = dc;
  }
  __syncthreads();
  float* fo = fout + ((size_t)(b * C + t)) * HW + (size_t)row * W + x0;
  #pragma unroll
  for (int p4 = 0; p4 < TW / 4; ++p4) {
    float4 v;
    v.x = acc[4 * p4 + 0] * invd_s[4 * p4 + 0];
    v.y = acc[4 * p4 + 1] * invd_s[4 * p4 + 1];
    v.z = acc[4 * p4 + 2] * invd_s[4 * p4 + 2];
    v.w = acc[4 * p4 + 3] * invd_s[4 * p4 + 3];
    *(float4*)(fo + 4 * p4) = v;
  }
}

extern "C" void kernel_launch(void* const* d_in, const int* in_sizes, int n_in,
                              void* d_out, int out_size, void* d_ws, size_t ws_size,
                              hipStream_t stream) {
  const float* pf = (const float*)d_in[0];
  const float* gd = (const float*)d_in[1];
  const float* K  = (const float*)d_in[2];
  const float* W1 = (const float*)d_in[3];
  const float* b1 = (const float*)d_in[4];
  const float* W2 = (const float*)d_in[5];
  const float* b2 = (const float*)d_in[6];
  // d_in[7]=H, d_in[8]=W are device ints; hardcoded below (grid needs them host-side)

  const int B = in_sizes[2] / 9;
  const int N = in_sizes[1] / (B * 14);
  const int C = in_sizes[0] / (B * N);
  const int H = 128, W = 224;

  float4* bbox = (float4*)d_ws;
  float4* prm  = bbox + (size_t)B * N;
  float*  hfe  = (float*)(prm + (size_t)B * N);

  float* out      = (float*)d_out;
  float* unc_out  = out + (size_t)B * C * H * W;
  float* dens_out = unc_out + (size_t)B * H * W;

  prep_kernel<<<dim3((B * N + 255) / 256), 256, 0, stream>>>(
      gd, K, bbox, prm, N, B, (float)W, (float)H);
  mlp_kernel<<<dim3(B * N), 256, 0, stream>>>(pf, W1, b1, W2, b2, hfe);
  splat_kernel<<<dim3(W / TW, H, B), 256, 0, stream>>>(
      bbox, prm, hfe, out, unc_out, dens_out, N, C, H, W);
}

// Round 2
// 164.209 us; speedup vs baseline: 1.1437x; 1.1437x over previous
//
#include <hip/hip_runtime.h>
#include <math.h>

// Shapes (from setup_inputs): B=2, N=512, C=256, H=128, W=224.
#define TW 56   // pixels per strip (224 = 4*56)
#define GC 32   // gaussians per LDS weight chunk
#define MAXN 1024
#define PTS 8   // points per MLP block

// ---------------- kernel 1: per-gaussian projection/prep ----------------
__global__ void prep_kernel(const float* __restrict__ gd,
                            const float* __restrict__ Kmat,
                            float4* __restrict__ bbox,
                            float4* __restrict__ prm,
                            int N, int B, float Wf, float Hf) {
  int i = blockIdx.x * blockDim.x + threadIdx.x;
  if (i >= B * N) return;
  int b = i / N;
  const float* g = gd + (size_t)i * 14;
  float X = g[0], Y = g[1], Z = g[2];
  float sigx = g[5], sigy = g[6], wt = g[12];
  const float* K = Kmat + (size_t)b * 9;
  float p0 = K[0]*X + K[1]*Y + K[2]*Z;
  float p1 = K[3]*X + K[4]*Y + K[5]*Z;
  float p2 = K[6]*X + K[7]*Y + K[8]*Z;
  float denom = p2 + 1e-6f;
  float p2x = p0 / denom, p2y = p1 / denom;
  float scale_x = Wf / K[2] * 0.5f;   // W / K[0,2] / 2
  float scale_y = Hf / K[5] * 0.5f;   // H / K[1,2] / 2
  float cx = p2x * scale_x;
  float cy = p2y * scale_y;
  bool valid = Z > 0.1f;
  bool inb = (cx >= 0.f) && (cx < Wf) && (cy >= 0.f) && (cy < Hf);
  bool active = valid && inb;
  float sxv = fmaxf(sigx * scale_x, 1.f);
  float syv = fmaxf(sigy * scale_y, 1.f);
  float wn = active ? wt : 0.f;
  float avg = 0.5f * (sxv + syv);
  if (active && wn != 0.f) {
    bbox[i] = make_float4(cx, cy, 3.f * sxv, 3.f * syv);
  } else {
    bbox[i] = make_float4(-1e30f, -1e30f, 0.f, 0.f);  // never culled-in
  }
  prm[i] = make_float4(1.f / sxv, 1.f / syv, wn, avg);
}

// ---------------- kernel 2: MLP h = relu(pf@W1^T+b1)@W2^T+b2 ----------------
// 8 points per block: W1/W2 L2 traffic amortized 8x; x reads are LDS broadcasts.
__global__ __launch_bounds__(256, 2) void mlp_kernel(
    const float* __restrict__ pf, const float* __restrict__ W1,
    const float* __restrict__ b1, const float* __restrict__ W2,
    const float* __restrict__ b2, float* __restrict__ hout, int npts) {
  const int t = threadIdx.x;            // output channel (C==256)
  const int p0 = blockIdx.x * PTS;
  __shared__ __align__(16) float xs[PTS][256];

  const float4* pf4 = (const float4*)(pf + (size_t)p0 * 256);
  float4* xs4 = (float4*)&xs[0][0];
  #pragma unroll
  for (int i = 0; i < PTS * 64 / 256; ++i) xs4[t + 256 * i] = pf4[t + 256 * i];
  __syncthreads();

  float acc[PTS];
  float bb1 = b1[t];
  #pragma unroll
  for (int p = 0; p < PTS; ++p) acc[p] = bb1;
  const float* w1r = W1 + (size_t)t * 256;
  for (int k = 0; k < 256; k += 4) {
    float4 w = *(const float4*)(w1r + k);
    #pragma unroll
    for (int p = 0; p < PTS; ++p) {
      float4 x = *(const float4*)(&xs[p][k]);
      acc[p] += w.x * x.x + w.y * x.y + w.z * x.z + w.w * x.w;
    }
  }
  __syncthreads();
  #pragma unroll
  for (int p = 0; p < PTS; ++p) xs[p][t] = fmaxf(acc[p], 0.f);
  __syncthreads();

  float acc2[PTS];
  float bb2 = b2[t];
  #pragma unroll
  for (int p = 0; p < PTS; ++p) acc2[p] = bb2;
  const float* w2r = W2 + (size_t)t * 256;
  for (int k = 0; k < 256; k += 4) {
    float4 w = *(const float4*)(w2r + k);
    #pragma unroll
    for (int p = 0; p < PTS; ++p) {
      float4 x = *(const float4*)(&xs[p][k]);
      acc2[p] += w.x * x.x + w.y * x.y + w.z * x.z + w.w * x.w;
    }
  }
  #pragma unroll
  for (int p = 0; p < PTS; ++p)
    if (p0 + p < npts) hout[((size_t)(p0 + p)) * 256 + t] = acc2[p];
}

// ---------------- kernel 3: gather-splat per 1x56 pixel strip ----------------
// block = 256 threads (thread = channel); one block owns strip (b,row,x0..x0+55)
// __launch_bounds__(256,2): VGPR cap 256 so acc[56] stays in registers (no spill).
__global__ __launch_bounds__(256, 2) void splat_kernel(
    const float4* __restrict__ bbox, const float4* __restrict__ prm,
    const float* __restrict__ hfeat, float* __restrict__ fout,
    float* __restrict__ unc_out, float* __restrict__ dens_out,
    int N, int C, int H, int W) {
  const int t = threadIdx.x;
  const int b = blockIdx.z;
  const int row = blockIdx.y;
  const int x0 = blockIdx.x * TW;
  const int HW = H * W;

  __shared__ int glist[MAXN];
  __shared__ __align__(16) float wlds[GC][TW];
  __shared__ float dens_s[TW], unc_s[TW], invd_s[TW], avgs_s[GC];
  __shared__ int wcnt[4];

  const float rf = (float)row;
  const float xlo = (float)x0, xhi = (float)(x0 + TW - 1);
  const int lane = t & 63, wave = t >> 6;
  const unsigned long long lmask = (1ull << lane) - 1ull;

  // ---- deterministic ordered cull (ballot + cross-wave prefix) ----
  int listlen = 0;
  for (int gb = 0; gb < N; gb += 256) {
    int g = gb + t;
    bool f = false;
    if (g < N) {
      float4 bb = bbox[(size_t)b * N + g];
      f = (bb.y - bb.w <= rf) && (bb.y + bb.w >= rf) &&
          (bb.x + bb.z >= xlo) && (bb.x - bb.z <= xhi);
    }
    unsigned long long m = __ballot(f);
    if (lane == 0) wcnt[wave] = __popcll(m);
    __syncthreads();
    int pre = 0;
    #pragma unroll
    for (int wv = 0; wv < 4; ++wv) pre += (wv < wave) ? wcnt[wv] : 0;
    int tot = wcnt[0] + wcnt[1] + wcnt[2] + wcnt[3];
    if (f) glist[listlen + pre + __popcll(m & lmask)] = g;
    __syncthreads();
    listlen += tot;
  }

  if (t < TW) { dens_s[t] = 0.f; unc_s[t] = 0.f; }
  float acc[TW];
  #pragma unroll
  for (int p = 0; p < TW; ++p) acc[p] = 0.f;
  __syncthreads();

  // ---- chunked accumulation ----
  for (int gs = 0; gs < listlen; gs += GC) {
    int gc = min(GC, listlen - gs);
    if (t < gc) avgs_s[t] = prm[(size_t)b * N + glist[gs + t]].w;
    // weights for gc gaussians x TW pixels
    for (int idx = t; idx < gc * TW; idx += 256) {
      int gi = idx / TW, p = idx - gi * TW;
      int g = glist[gs + gi];
      float4 bb = bbox[(size_t)b * N + g];
      float4 pr = prm[(size_t)b * N + g];
      float dx = (xlo + (float)p - bb.x) * pr.x;
      float dy = (rf - bb.y) * pr.y;
      float d = dx * dx + dy * dy;
      wlds[gi][p] = (d < 9.f) ? __expf(-0.5f * d) * pr.z : 0.f;
    }
    __syncthreads();
    // per-pixel density / uncertainty (56 threads, overlapped with feature loop waves)
    if (t < TW) {
      float dsum = dens_s[t], usum = unc_s[t];
      for (int gi = 0; gi < gc; ++gi) {
        float w = wlds[gi][t];
        dsum += w;
        usum += w * avgs_s[gi];
      }
      dens_s[t] = dsum; unc_s[t] = usum;
    }
    // per-channel feature accumulation (broadcast LDS reads)
    for (int gi = 0; gi < gc; ++gi) {
      float hv = hfeat[((size_t)b * N + glist[gs + gi]) * C + t];
      const float4* wr = (const float4*)&wlds[gi][0];
      #pragma unroll
      for (int p4 = 0; p4 < TW / 4; ++p4) {
        float4 w4 = wr[p4];
        acc[4 * p4 + 0] += w4.x * hv;
        acc[4 * p4 + 1] += w4.y * hv;
        acc[4 * p4 + 2] += w4.z * hv;
        acc[4 * p4 + 3] += w4.w * hv;
      }
    }
    __syncthreads();
  }

  // ---- normalize + write ----
  if (t < TW) {
    float dc = fmaxf(dens_s[t], 1e-6f);
    float inv = 1.f / dc;
    invd_s[t] = inv;
    size_t pix = (size_t)b * HW + (size_t)row * W + x0 + t;
    unc_out[pix] = unc_s[t] * inv;
    dens_out[pix] = dc;
  }
  __syncthreads();
  float* fo = fout + ((size_t)(b * C + t)) * HW + (size_t)row * W + x0;
  #pragma unroll
  for (int p4 = 0; p4 < TW / 4; ++p4) {
    float4 v;
    v.x = acc[4 * p4 + 0] * invd_s[4 * p4 + 0];
    v.y = acc[4 * p4 + 1] * invd_s[4 * p4 + 1];
    v.z = acc[4 * p4 + 2] * invd_s[4 * p4 + 2];
    v.w = acc[4 * p4 + 3] * invd_s[4 * p4 + 3];
    *(float4*)(fo + 4 * p4) = v;
  }
}

extern "C" void kernel_launch(void* const* d_in, const int* in_sizes, int n_in,
                              void* d_out, int out_size, void* d_ws, size_t ws_size,
                              hipStream_t stream) {
  const float* pf = (const float*)d_in[0];
  const float* gd = (const float*)d_in[1];
  const float* K  = (const float*)d_in[2];
  const float* W1 = (const float*)d_in[3];
  const float* b1 = (const float*)d_in[4];
  const float* W2 = (const float*)d_in[5];
  const float* b2 = (const float*)d_in[6];

  const int B = in_sizes[2] / 9;
  const int N = in_sizes[1] / (B * 14);
  const int C = in_sizes[0] / (B * N);
  const int H = 128, W = 224;

  float4* bbox = (float4*)d_ws;
  float4* prm  = bbox + (size_t)B * N;
  float*  hfe  = (float*)(prm + (size_t)B * N);

  float* out      = (float*)d_out;
  float* unc_out  = out + (size_t)B * C * H * W;
  float* dens_out = unc_out + (size_t)B * H * W;

  prep_kernel<<<dim3((B * N + 255) / 256), 256, 0, stream>>>(
      gd, K, bbox, prm, N, B, (float)W, (float)H);
  mlp_kernel<<<dim3((B * N + PTS - 1) / PTS), 256, 0, stream>>>(
      pf, W1, b1, W2, b2, hfe, B * N);
  splat_kernel<<<dim3(W / TW, H, B), 256, 0, stream>>>(
      bbox, prm, hfe, out, unc_out, dens_out, N, C, H, W);
}